// Round 1
// baseline (81.743 us; speedup 1.0000x reference)
//
#include <hip/hip_runtime.h>
#include <float.h>

#define BATCH 8
#define SEQ   1024
#define FDIM  16
#define NFEAT 11
#define ROWS  16          // query rows per block
#define COLS  4           // key columns per thread (SEQ / 256)

__global__ __launch_bounds__(256, 2)
void featsim_kernel(const float* __restrict__ x,
                    const int* __restrict__ lengths,
                    const float* __restrict__ w,
                    float* __restrict__ out) {
    const int tid = threadIdx.x;
    const int b  = blockIdx.x >> 6;          // SEQ/ROWS == 64 tiles per batch
    const int i0 = (blockIdx.x & 63) * ROWS;
    const int len = lengths[b];

    __shared__ float q_lds[ROWS][12];        // pad 11 -> 12 (16B-aligned rows)
    __shared__ float redbuf[4][ROWS];
    __shared__ float rowmax[ROWS];
    __shared__ float rowinv[ROWS];

    // ---- stage the 16 query rows (11 features each) into LDS ----
    if (tid < ROWS * NFEAT) {
        int r = tid / NFEAT, k = tid - r * NFEAT;
        q_lds[r][k] = x[(size_t)(b * SEQ + i0 + r) * FDIM + k];
    }
    __syncthreads();

    // feature importance -> (wave-uniform, lands in SGPRs)
    float wreg[NFEAT];
    #pragma unroll
    for (int k = 0; k < NFEAT; ++k) wreg[k] = w[k];

    // ---- load this thread's 4 key rows (vectorized, L2-resident) ----
    float xj[COLS][12];
    #pragma unroll
    for (int c = 0; c < COLS; ++c) {
        int j = tid + c * 256;
        const float4* p = (const float4*)(x + (size_t)(b * SEQ + j) * FDIM);
        float4 f0 = p[0], f1 = p[1], f2 = p[2];
        xj[c][0] = f0.x; xj[c][1] = f0.y; xj[c][2]  = f0.z; xj[c][3]  = f0.w;
        xj[c][4] = f1.x; xj[c][5] = f1.y; xj[c][6]  = f1.z; xj[c][7]  = f1.w;
        xj[c][8] = f2.x; xj[c][9] = f2.y; xj[c][10] = f2.z; xj[c][11] = f2.w;
    }

    // ---- scores: acc[r][c] = sum_k |q[r][k] - xj[c][k]| * w[k] ----
    float acc[ROWS][COLS];
    #pragma unroll
    for (int r = 0; r < ROWS; ++r) {
        float qr[NFEAT];
        #pragma unroll
        for (int k = 0; k < NFEAT; ++k) qr[k] = q_lds[r][k];
        #pragma unroll
        for (int c = 0; c < COLS; ++c) {
            float a = 0.f;
            #pragma unroll
            for (int k = 0; k < NFEAT; ++k)
                a += fabsf(qr[k] - xj[c][k]) * wreg[k];
            acc[r][c] = a;
        }
    }

    const int lane = tid & 63;
    const int wv   = tid >> 6;

    // ---- row max (masked) ----
    #pragma unroll
    for (int r = 0; r < ROWS; ++r) {
        float m = -FLT_MAX;
        #pragma unroll
        for (int c = 0; c < COLS; ++c) {
            int j = tid + c * 256;
            if (j < len) m = fmaxf(m, acc[r][c]);
        }
        #pragma unroll
        for (int o = 32; o > 0; o >>= 1) m = fmaxf(m, __shfl_xor(m, o, 64));
        if (lane == 0) redbuf[wv][r] = m;
    }
    __syncthreads();
    if (tid < ROWS) {
        rowmax[tid] = fmaxf(fmaxf(redbuf[0][tid], redbuf[1][tid]),
                            fmaxf(redbuf[2][tid], redbuf[3][tid]));
    }
    __syncthreads();

    // ---- exp + row sum ----
    #pragma unroll
    for (int r = 0; r < ROWS; ++r) {
        float m = rowmax[r];
        float s = 0.f;
        #pragma unroll
        for (int c = 0; c < COLS; ++c) {
            int j = tid + c * 256;
            float e = (j < len) ? __expf(acc[r][c] - m) : 0.f;
            acc[r][c] = e;
            s += e;
        }
        #pragma unroll
        for (int o = 32; o > 0; o >>= 1) s += __shfl_xor(s, o, 64);
        if (lane == 0) redbuf[wv][r] = s;
    }
    __syncthreads();
    if (tid < ROWS) {
        float s = redbuf[0][tid] + redbuf[1][tid] + redbuf[2][tid] + redbuf[3][tid];
        rowinv[tid] = 1.f / s;
    }
    __syncthreads();

    // ---- normalize + coalesced store ----
    #pragma unroll
    for (int r = 0; r < ROWS; ++r) {
        float inv = rowinv[r];
        size_t base = (size_t)(b * SEQ + i0 + r) * SEQ;
        #pragma unroll
        for (int c = 0; c < COLS; ++c)
            out[base + tid + c * 256] = acc[r][c] * inv;
    }
}

extern "C" void kernel_launch(void* const* d_in, const int* in_sizes, int n_in,
                              void* d_out, int out_size, void* d_ws, size_t ws_size,
                              hipStream_t stream) {
    const float* x       = (const float*)d_in[0];
    const int*   lengths = (const int*)d_in[1];
    const float* w       = (const float*)d_in[2];
    float*       out     = (float*)d_out;

    featsim_kernel<<<dim3(BATCH * (SEQ / ROWS)), dim3(256), 0, stream>>>(
        x, lengths, w, out);
}